// Round 4
// baseline (334.982 us; speedup 1.0000x reference)
//
#include <hip/hip_runtime.h>

// DigitCaps dynamic routing, MI355X — round 4.
// vs round 3: (1) CHUNK=2 softmax batching (16 barrier rounds/pass, full-width
// softmax), (2) W bf16 conversion fused into pass A (conv_w deleted),
// (3) partial-sum outputs + fused reduce in squash (atomics & memsets deleted).
//
// u_hat[b,j,i,p] = sum_q x[b,i,q] W[j,i,p,q];  b=64, i=2048, j=32, p=32, q=16
// Pass A: s1 = (1/32) sum_i u_hat ; v1 = squash(s1)       (also emits Wt bf16)
// Pass B: d1 = sum_p v1*u_hat ; c2 = softmax_j(d1) ; s2 ; v2 = squash(s2)
// Pass C: b3 = d1+d2 = sum_p (v1+v2)*u_hat  (linearity) ; out = squash(s3)
//
// MFMA 16x16x32 bf16: A k0-15 = hi(x), k16-31 = lo residual; B k-halves
// replicate W  => A-side fp32-exact, only W rounded once.

namespace {

using bfrag = __attribute__((ext_vector_type(8))) short;   // 8 bf16 = 4 VGPR
using ffrag = __attribute__((ext_vector_type(4))) float;   // 4 fp32 acc

constexpr int I_DIM = 2048;
constexpr int B_DIM = 64;
constexpr int N_DIM = 1024;     // j*32+p
constexpr int TI    = 16;       // i's per block
constexpr int NIT   = I_DIM / TI;   // 128 i-tiles

__device__ __forceinline__ unsigned short f2bf(float f) {
    unsigned int u = __float_as_uint(f);
    return (unsigned short)((u + 0x7fffu + ((u >> 16) & 1u)) >> 16);
}

// DPP row_ror reductions within 16-lane rows — pure VALU, no LDS pipe.
template<int CTRL>
__device__ __forceinline__ float dppf(float x) {
    return __int_as_float(
        __builtin_amdgcn_update_dpp(0, __float_as_int(x), CTRL, 0xF, 0xF, true));
}
__device__ __forceinline__ float sum16(float x) {
    x += dppf<0x121>(x); x += dppf<0x122>(x);
    x += dppf<0x124>(x); x += dppf<0x128>(x);
    return x;
}
__device__ __forceinline__ float max16(float x) {
    x = fmaxf(x, dppf<0x121>(x)); x = fmaxf(x, dppf<0x122>(x));
    x = fmaxf(x, dppf<0x124>(x)); x = fmaxf(x, dppf<0x128>(x));
    return x;
}

// xT2[i][b][0:16]=hi(x), [16:32]=lo residual  <-  x[b][i][q] fp32
__global__ __launch_bounds__(256)
void conv_x(const float* __restrict__ x, unsigned short* __restrict__ xT2) {
    const int t = blockIdx.x * 256 + threadIdx.x;          // (i,b)
    const int i = t >> 6, b = t & 63;
    const float* src = x + (((size_t)b * I_DIM + i) << 4);
    unsigned int o[16];
    #pragma unroll
    for (int k = 0; k < 8; ++k) {
        const float f0 = src[2 * k], f1 = src[2 * k + 1];
        const unsigned short h0 = f2bf(f0), h1 = f2bf(f1);
        const float l0 = f0 - __uint_as_float(((unsigned int)h0) << 16);
        const float l1 = f1 - __uint_as_float(((unsigned int)h1) << 16);
        o[k]     = (unsigned int)h0       | ((unsigned int)h1 << 16);
        o[8 + k] = (unsigned int)f2bf(l0) | ((unsigned int)f2bf(l1) << 16);
    }
    uint4* dst = reinterpret_cast<uint4*>(xT2 + (size_t)t * 32);
    #pragma unroll
    for (int k = 0; k < 4; ++k)
        dst[k] = make_uint4(o[4 * k], o[4 * k + 1], o[4 * k + 2], o[4 * k + 3]);
}

// ---------------- routing pass ----------------
// Block: 1024 thr = 16 waves, one 16-b group, all 32 j (2 j per wave), TI i's.
// ROUTED=false (pass A): reads fp32 W, converts, writes Wt (bg0 only), uniform c.
// ROUTED=true  (B/C):    reads Wt bf16; CHUNK=2 cross-wave softmax.
template<bool ROUTED>
__global__ __launch_bounds__(1024)
void caps_pass(const float* __restrict__ Wf,            // [J][I][P][Q] fp32
               unsigned short* __restrict__ Wt,         // [I][N][16] bf16
               const unsigned short* __restrict__ xT2,  // [I][64][32] bf16
               const float* __restrict__ v_in,          // [64][32][32] or null
               float* __restrict__ s_part)              // [NIT][64][1024]
{
    __shared__ float d_buf[32 * 33];
    __shared__ float c_buf[32 * 33];

    const int tid = threadIdx.x;
    const int w   = tid >> 6;          // wave 0..15
    const int l   = tid & 63;
    const int g   = l >> 4;            // 16-lane group 0..3
    const int li  = l & 15;
    const int j0  = w << 1;            // 2 j per wave
    const int qb  = (g & 1) << 3;      // B k-replication: q base 0/8
    const int g8  = g << 3;            // A k offset (hi 0-15, lo 16-31)

    // XCD-chunked bijective swizzle (512 blocks, 512%8==0).
    const int bid = (int)blockIdx.x;
    const int V   = (bid & 7) * 64 + (bid >> 3);
    const int it  = V >> 2;
    const int b0  = (V & 3) << 4;

    const unsigned short* pa = xT2 + (b0 + li) * 32 + g8;

    ffrag s[4];
    #pragma unroll
    for (int t = 0; t < 4; ++t) s[t] = ffrag{0.f, 0.f, 0.f, 0.f};

    if constexpr (ROUTED) {
        // v in registers: vr[r][t] = v[b0+4g+r][j0+(t>>1)][(t&1)*16+li]
        float vr[4][4];
        #pragma unroll
        for (int r = 0; r < 4; ++r)
            #pragma unroll
            for (int t = 0; t < 4; ++t)
                vr[r][t] = v_in[((b0 + (g << 2) + r) * 32 + j0 + (t >> 1)) * 32
                                + ((t & 1) << 4) + li];

        const unsigned short* pb[4];
        #pragma unroll
        for (int t = 0; t < 4; ++t)
            pb[t] = Wt + (size_t)((((j0 + (t >> 1)) << 5) + ((t & 1) << 4) + li) * 16 + qb);

        // prologue: frags for chunk 0 (i = it*16, it*16+1)
        bfrag afn[2], bfn[2][4];
        #pragma unroll
        for (int ic = 0; ic < 2; ++ic) {
            const size_t i0 = (size_t)(it * TI + ic);
            afn[ic] = *reinterpret_cast<const bfrag*>(pa + (i0 << 11));
            #pragma unroll
            for (int t = 0; t < 4; ++t)
                bfn[ic][t] = *reinterpret_cast<const bfrag*>(pb[t] + (i0 << 14));
        }

        for (int cc = 0; cc < TI / 2; ++cc) {
            // consume current frags
            ffrag u[2][4];
            #pragma unroll
            for (int ic = 0; ic < 2; ++ic)
                #pragma unroll
                for (int t = 0; t < 4; ++t) {
                    ffrag z{0.f, 0.f, 0.f, 0.f};
                    u[ic][t] = __builtin_amdgcn_mfma_f32_16x16x32_bf16(
                        afn[ic], bfn[ic][t], z, 0, 0, 0);
                }

            // prefetch next chunk (last chunk reloads itself — harmless)
            const int inext = it * TI + ((cc < TI / 2 - 1) ? 2 * cc + 2 : 2 * cc);
            #pragma unroll
            for (int ic = 0; ic < 2; ++ic) {
                const size_t i0 = (size_t)(inext + ic);
                afn[ic] = *reinterpret_cast<const bfrag*>(pa + (i0 << 11));
                #pragma unroll
                for (int t = 0; t < 4; ++t)
                    bfn[ic][t] = *reinterpret_cast<const bfrag*>(pb[t] + (i0 << 14));
            }
            asm volatile("" ::: "memory");

            // d[b,j] = sum_p v*u  (DPP 16-lane reduce, p = (t&1)*16+li)
            #pragma unroll
            for (int ic = 0; ic < 2; ++ic)
                #pragma unroll
                for (int r = 0; r < 4; ++r) {
                    float d0 = u[ic][0][r] * vr[r][0] + u[ic][1][r] * vr[r][1];
                    float d1 = u[ic][2][r] * vr[r][2] + u[ic][3][r] * vr[r][3];
                    d0 = sum16(d0);
                    d1 = sum16(d1);
                    const float dsel = (li & 1) ? d1 : d0;
                    if (li < 2)
                        d_buf[((ic << 4) + (g << 2) + r) * 33 + j0 + li] = dsel;
                }

            // raw barrier: drain LDS only — global prefetch stays in flight
            asm volatile("s_waitcnt lgkmcnt(0)\n\ts_barrier" ::: "memory");

            // softmax over j: 32 rows x 32 j = all 1024 threads
            {
                const int row = tid >> 5, jx = tid & 31;
                const float bn = d_buf[row * 33 + jx];
                float m = max16(bn);
                m = fmaxf(m, __shfl_xor(m, 16));
                const float e = __expf(bn - m);
                float ssum = sum16(e);
                ssum += __shfl_xor(ssum, 16);
                c_buf[row * 33 + jx] = e / ssum;
            }

            asm volatile("s_waitcnt lgkmcnt(0)\n\ts_barrier" ::: "memory");

            // s += c * u (8 broadcast LDS reads per wave per chunk-half)
            #pragma unroll
            for (int ic = 0; ic < 2; ++ic)
                #pragma unroll
                for (int r = 0; r < 4; ++r) {
                    const float c0 = c_buf[((ic << 4) + (g << 2) + r) * 33 + j0];
                    const float c1 = c_buf[((ic << 4) + (g << 2) + r) * 33 + j0 + 1];
                    s[0][r] += c0 * u[ic][0][r];
                    s[1][r] += c0 * u[ic][1][r];
                    s[2][r] += c1 * u[ic][2][r];
                    s[3][r] += c1 * u[ic][3][r];
                }
        }
    } else {
        // pass A: uniform c. Read fp32 W, convert (same f2bf as Wt), write Wt
        // once (bg0, groups 0-1), accumulate via MFMA C operand.
        for (int ii = 0; ii < TI; ++ii) {
            const int i = it * TI + ii;
            const bfrag a = *reinterpret_cast<const bfrag*>(pa + ((size_t)i << 11));
            #pragma unroll
            for (int t = 0; t < 4; ++t) {
                const int jj = j0 + (t >> 1);
                const int nl = ((t & 1) << 4) + li;          // n & 31
                const float* wp = Wf + (((size_t)jj * I_DIM + i) << 9) + nl * 16 + qb;
                const float4 wa = reinterpret_cast<const float4*>(wp)[0];
                const float4 wb = reinterpret_cast<const float4*>(wp)[1];
                bfrag bf;
                bf[0] = (short)f2bf(wa.x); bf[1] = (short)f2bf(wa.y);
                bf[2] = (short)f2bf(wa.z); bf[3] = (short)f2bf(wa.w);
                bf[4] = (short)f2bf(wb.x); bf[5] = (short)f2bf(wb.y);
                bf[6] = (short)f2bf(wb.z); bf[7] = (short)f2bf(wb.w);
                if (b0 == 0 && g < 2) {
                    *reinterpret_cast<bfrag*>(
                        Wt + ((((size_t)i << 10) + (jj << 5) + nl) << 4) + qb) = bf;
                }
                s[t] = __builtin_amdgcn_mfma_f32_16x16x32_bf16(a, bf, s[t], 0, 0, 0);
            }
        }
    }

    // write partial tile (overwrite, no atomics; every slot covered)
    const float sc = ROUTED ? 1.f : (1.f / 32.f);
    #pragma unroll
    for (int t = 0; t < 4; ++t)
        #pragma unroll
        for (int r = 0; r < 4; ++r)
            s_part[((size_t)it * B_DIM + b0 + (g << 2) + r) * N_DIM
                   + ((j0 + (t >> 1)) << 5) + ((t & 1) << 4) + li] = s[t][r] * sc;
}

// dst[row] = (base ? base[row] : 0) + squash(sum_it s_part[it][row]),  row=(b,j)
__global__ __launch_bounds__(256)
void squash_reduce(const float* __restrict__ s_part,
                   const float* __restrict__ base,
                   float* __restrict__ dst) {
    const int tid = threadIdx.x;
    const int rr  = blockIdx.x * 8 + (tid >> 5);   // row 0..2047
    const int p   = tid & 31;
    const int b   = rr >> 5, j = rr & 31;
    const float* sp = s_part + (size_t)b * N_DIM + (j << 5) + p;
    float a0 = 0.f, a1 = 0.f, a2 = 0.f, a3 = 0.f;
    for (int it2 = 0; it2 < NIT; it2 += 4) {
        a0 += sp[(size_t)(it2 + 0) << 16];
        a1 += sp[(size_t)(it2 + 1) << 16];
        a2 += sp[(size_t)(it2 + 2) << 16];
        a3 += sp[(size_t)(it2 + 3) << 16];
    }
    const float sv = (a0 + a1) + (a2 + a3);
    float n2 = sv * sv;
    n2 = sum16(n2);
    n2 += __shfl_xor(n2, 16);
    const float scl = n2 / ((1.f + n2) * sqrtf(n2 + 1e-7f));
    dst[rr * 32 + p] = (base ? base[rr * 32 + p] : 0.f) + scl * sv;
}

} // namespace

extern "C" void kernel_launch(void* const* d_in, const int* in_sizes, int n_in,
                              void* d_out, int out_size, void* d_ws, size_t ws_size,
                              hipStream_t stream) {
    const float* x = (const float*)d_in[0];   // [64, 2048, 16]
    const float* W = (const float*)d_in[1];   // [32, 2048, 32, 16]
    float* out = (float*)d_out;               // [64, 32, 32]

    const size_t needW = (size_t)I_DIM * N_DIM * 16 * 2;      // 64 MB bf16 Wt
    const size_t needX = (size_t)I_DIM * B_DIM * 32 * 2;      // 8 MB bf16 xT2
    const size_t needP = (size_t)NIT * B_DIM * N_DIM * 4;     // 32 MB partials
    const size_t needV = (size_t)B_DIM * N_DIM * 4;           // 256 KB

    char* pp = (char*)d_ws;
    unsigned short* Wt  = (unsigned short*)pp; pp += needW;
    unsigned short* xT2 = (unsigned short*)pp; pp += needX;
    float* s_part = (float*)pp; pp += needP;
    float* v1     = (float*)pp; pp += needV;
    float* vs     = (float*)pp;
    (void)needX; (void)ws_size;

    conv_x<<<(I_DIM * B_DIM) / 256, 256, 0, stream>>>(x, xT2);

    const dim3 rg(512), rb(1024);
    const dim3 qg(256), qb(256);

    // pass A: uniform c = 1/32; also emits Wt
    caps_pass<false><<<rg, rb, 0, stream>>>(W, Wt, xT2, nullptr, s_part);
    squash_reduce<<<qg, qb, 0, stream>>>(s_part, nullptr, v1);

    // pass B: v = v1
    caps_pass<true><<<rg, rb, 0, stream>>>(W, Wt, xT2, v1, s_part);
    squash_reduce<<<qg, qb, 0, stream>>>(s_part, v1, vs);      // vs = v1 + v2

    // pass C: v = v1+v2 (b3 = d1+d2 is linear in v)
    caps_pass<true><<<rg, rb, 0, stream>>>(W, Wt, xT2, vs, s_part);
    squash_reduce<<<qg, qb, 0, stream>>>(s_part, nullptr, out);
}